// Round 1
// baseline (75599.133 us; speedup 1.0000x reference)
//
#include <hip/hip_runtime.h>
#include <stdint.h>

#define S_LEN 16384
#define HID 2048
#define NPAIR 1024   // h pairs (2048/2)

typedef _Float16 h2v __attribute__((ext_vector_type(2)));

__device__ __forceinline__ float dot2f(uint32_t a, uint32_t b, float c) {
#if __has_builtin(__builtin_amdgcn_fdot2)
  return __builtin_amdgcn_fdot2(__builtin_bit_cast(h2v, a), __builtin_bit_cast(h2v, b), c, false);
#else
  h2v ha = __builtin_bit_cast(h2v, a), hb = __builtin_bit_cast(h2v, b);
  return c + (float)ha[0] * (float)hb[0] + (float)ha[1] * (float)hb[1];
#endif
}

__device__ __forceinline__ uint32_t packh2(float a, float b) {
  h2v h; h[0] = (_Float16)a; h[1] = (_Float16)b;
  return __builtin_bit_cast(uint32_t, h);
}

__device__ __forceinline__ float fsig(float x) { return 1.0f / (1.0f + __expf(-x)); }
__device__ __forceinline__ float ftanh(float x) { return 2.0f / (1.0f + __expf(-2.0f * x)) - 1.0f; }

// ---------------- Phase A: QCNN MLP per token + hbuf init ----------------
__global__ __launch_bounds__(256) void qcnn_kernel(
    const float* __restrict__ sent,
    const float* __restrict__ fm_w, const float* __restrict__ fm_b,
    const float* __restrict__ c1w, const float* __restrict__ c1b,
    const float* __restrict__ p1w, const float* __restrict__ p1b,
    const float* __restrict__ c2w, const float* __restrict__ c2b,
    const float* __restrict__ p2w, const float* __restrict__ p2b,
    const float* __restrict__ c3w, const float* __restrict__ c3b,
    const float* __restrict__ hw, const float* __restrict__ hb,
    float* __restrict__ seq, unsigned long long* __restrict__ hbuf) {
  __shared__ float w[720];
  const int tid = threadIdx.x;
  const float* srcs[14] = {fm_w, fm_b, c1w, c1b, p1w, p1b, c2w, c2b, p2w, p2b, c3w, c3b, hw, hb};
  const int offs[14] = {0, 128, 144, 400, 416, 608, 620, 668, 672, 688, 692, 708, 712, 716};
  const int cnts[14] = {128, 16, 256, 16, 192, 12, 48, 4, 16, 4, 16, 4, 4, 1};
  for (int a = 0; a < 14; ++a)
    for (int i = tid; i < cnts[a]; i += 256) w[offs[a] + i] = srcs[a][i];
  if (blockIdx.x == 0) {
    // init h ring buffer: slot0 = h(-1)=0 with tag 0; slot1 = invalid tag
    for (int p = tid; p < NPAIR; p += 256) {
      hbuf[p] = 0ull;
      hbuf[NPAIR + p] = 0x7FFFFFFFull << 32;
    }
  }
  __syncthreads();
  const int t = blockIdx.x * 256 + tid;
  float x[8];
#pragma unroll
  for (int i = 0; i < 8; ++i) x[i] = sent[t * 8 + i];
  float a0[16], a1[16], a2[12], a3[4], a4[4], a5[4];
#pragma unroll
  for (int o = 0; o < 16; ++o) {
    float s = w[128 + o];
#pragma unroll
    for (int i = 0; i < 8; ++i) s += x[i] * w[i * 16 + o];
    a0[o] = ftanh(s);
  }
#pragma unroll
  for (int o = 0; o < 16; ++o) {
    float s = w[400 + o];
#pragma unroll
    for (int i = 0; i < 16; ++i) s += a0[i] * w[144 + i * 16 + o];
    a1[o] = ftanh(s);
  }
#pragma unroll
  for (int o = 0; o < 12; ++o) {
    float s = w[608 + o];
#pragma unroll
    for (int i = 0; i < 16; ++i) s += a1[i] * w[416 + i * 12 + o];
    a2[o] = ftanh(s);
  }
#pragma unroll
  for (int o = 0; o < 4; ++o) {
    float s = w[668 + o];
#pragma unroll
    for (int i = 0; i < 12; ++i) s += a2[i] * w[620 + i * 4 + o];
    a3[o] = ftanh(s);
  }
#pragma unroll
  for (int o = 0; o < 4; ++o) {
    float s = w[688 + o];
#pragma unroll
    for (int i = 0; i < 4; ++i) s += a3[i] * w[672 + i * 4 + o];
    a4[o] = ftanh(s);
  }
#pragma unroll
  for (int o = 0; o < 4; ++o) {
    float s = w[708 + o];
#pragma unroll
    for (int i = 0; i < 4; ++i) s += a4[i] * w[692 + i * 4 + o];
    a5[o] = ftanh(s);
  }
  float s = w[716];
#pragma unroll
  for (int i = 0; i < 4; ++i) s += a5[i] * w[712 + i];
  seq[t] = fsig(s);
}

// ---------------- Phase B: persistent LSTM scan ----------------
// 256 blocks (1/CU forced via 139.5KB LDS). Block b owns h[8b..8b+8).
// Gate weights (columns of wf/wi/wu/wo) live in LDS as packed-f16 h-pairs.
// Cross-block h exchange: self-tagged u64 atomics {tag = step+1, f16 h-pair},
// double-buffered by step parity. No grid barrier; consumers spin on tags.
__global__ __launch_bounds__(256, 1) void lstm_kernel(
    const float* __restrict__ seq,
    const float* __restrict__ wfp, const float* __restrict__ bfp,
    const float* __restrict__ wip, const float* __restrict__ bip,
    const float* __restrict__ wup, const float* __restrict__ bup,
    const float* __restrict__ wop, const float* __restrict__ bop,
    unsigned long long* __restrict__ hbuf,
    uint32_t* __restrict__ hseq) {
  __shared__ __align__(16) uint32_t wgt[8 * 1024 * 4];  // 128KB: [jj][pair][gate f,i,u,o]
  __shared__ uint32_t hlds[2 * NPAIR];                  // 8KB: h pairs, per parity
  __shared__ float scal[64];                            // wx[jj*4+g], b at +32
  const int tid = threadIdx.x;
  const int lane = tid & 63;
  const int wv = tid >> 6;
  const int blk = blockIdx.x;
  const float* wptr[4] = {wfp, wip, wup, wop};
  const float* bptr[4] = {bfp, bip, bup, bop};
  {
    const int jj = tid & 7;
    const int col = blk * 8 + jj;
    const int pb = tid >> 3;
#pragma unroll
    for (int g = 0; g < 4; ++g) {
      const float* wsp = wptr[g];
      for (int pp = 0; pp < 32; ++pp) {
        int p = pp * 32 + pb;
        float w0 = wsp[(size_t)(1 + 2 * p) * HID + col];  // rows 1.. are h coeffs
        float w1 = wsp[(size_t)(2 + 2 * p) * HID + col];
        wgt[(jj * 1024 + p) * 4 + g] = packh2(w0, w1);
      }
    }
  }
  if (tid < 32) {
    int jj = tid & 7, g = tid >> 3;
    int col = blk * 8 + jj;
    scal[jj * 4 + g] = wptr[g][col];       // row 0 = x coefficient
    scal[32 + jj * 4 + g] = bptr[g][col];  // bias
  }
  __syncthreads();
  const int jjA = wv * 2, jjB = jjA + 1;
  float wxA[4], wxB[4], bbA[4], bbB[4];
#pragma unroll
  for (int g = 0; g < 4; ++g) {
    wxA[g] = scal[jjA * 4 + g]; bbA[g] = scal[32 + jjA * 4 + g];
    wxB[g] = scal[jjB * 4 + g]; bbB[g] = scal[32 + jjB * 4 + g];
  }
  float cA = 0.f, cB = 0.f;
  const uint4* w4 = (const uint4*)wgt;
  const int myslot = blk * 4 + wv;

  for (int s = 0; s < S_LEN; ++s) {
    const int slot = s & 1;
    if (wv == 0) {
      // wave 0 gathers h(s-1): poll tagged u64s, bounce payload into LDS
      unsigned long long* src = hbuf + (size_t)slot * NPAIR;
      unsigned long long hv[16];
#pragma unroll
      for (int k = 0; k < 16; ++k)
        hv[k] = __hip_atomic_load(src + k * 64 + lane, __ATOMIC_RELAXED, __HIP_MEMORY_SCOPE_AGENT);
      while (true) {
        unsigned bad = 0;
#pragma unroll
        for (int k = 0; k < 16; ++k)
          if ((uint32_t)(hv[k] >> 32) != (uint32_t)s) bad |= 1u << k;
        if (!bad) break;
        __builtin_amdgcn_s_sleep(1);
#pragma unroll
        for (int k = 0; k < 16; ++k)
          if (bad & (1u << k))
            hv[k] = __hip_atomic_load(src + k * 64 + lane, __ATOMIC_RELAXED, __HIP_MEMORY_SCOPE_AGENT);
      }
#pragma unroll
      for (int k = 0; k < 16; ++k) hlds[slot * NPAIR + k * 64 + lane] = (uint32_t)hv[k];
    }
    __syncthreads();
    float acc[2][4] = {{0.f, 0.f, 0.f, 0.f}, {0.f, 0.f, 0.f, 0.f}};
    const uint32_t* hp = hlds + slot * NPAIR;
#pragma unroll
    for (int k = 0; k < 16; ++k) {
      uint32_t hh = hp[k * 64 + lane];
      uint4 wa = w4[jjA * 1024 + k * 64 + lane];
      acc[0][0] = dot2f(wa.x, hh, acc[0][0]);
      acc[0][1] = dot2f(wa.y, hh, acc[0][1]);
      acc[0][2] = dot2f(wa.z, hh, acc[0][2]);
      acc[0][3] = dot2f(wa.w, hh, acc[0][3]);
      uint4 wb = w4[jjB * 1024 + k * 64 + lane];
      acc[1][0] = dot2f(wb.x, hh, acc[1][0]);
      acc[1][1] = dot2f(wb.y, hh, acc[1][1]);
      acc[1][2] = dot2f(wb.z, hh, acc[1][2]);
      acc[1][3] = dot2f(wb.w, hh, acc[1][3]);
    }
#pragma unroll
    for (int m = 32; m >= 1; m >>= 1)
#pragma unroll
      for (int j = 0; j < 2; ++j)
#pragma unroll
        for (int g = 0; g < 4; ++g) acc[j][g] += __shfl_xor(acc[j][g], m, 64);
    const float xt = seq[s];
    float pF = acc[0][0] + wxA[0] * xt + bbA[0];
    float pI = acc[0][1] + wxA[1] * xt + bbA[1];
    float pU = acc[0][2] + wxA[2] * xt + bbA[2];
    float pO = acc[0][3] + wxA[3] * xt + bbA[3];
    cA = fsig(pF) * cA + fsig(pI) * ftanh(pU);
    const float hA = fsig(pO) * ftanh(cA);
    pF = acc[1][0] + wxB[0] * xt + bbB[0];
    pI = acc[1][1] + wxB[1] * xt + bbB[1];
    pU = acc[1][2] + wxB[2] * xt + bbB[2];
    pO = acc[1][3] + wxB[3] * xt + bbB[3];
    cB = fsig(pF) * cB + fsig(pI) * ftanh(pU);
    const float hB = fsig(pO) * ftanh(cB);
    if (lane == 0) {
      const uint32_t pk = packh2(hA, hB);
      hseq[(size_t)s * NPAIR + myslot] = pk;
      const unsigned long long val =
          (((unsigned long long)(uint32_t)(s + 1)) << 32) | (unsigned long long)pk;
      __hip_atomic_store(hbuf + (size_t)((s + 1) & 1) * NPAIR + myslot, val,
                         __ATOMIC_RELAXED, __HIP_MEMORY_SCOPE_AGENT);
    }
  }
}

// ---------------- Phase C: wt pre-pack to f16 pairs ----------------
__global__ __launch_bounds__(256) void packwt_kernel(const float* __restrict__ wt,
                                                     uint32_t* __restrict__ wtp) {
  const int idx = blockIdx.x * 256 + threadIdx.x;  // p*2048 + n, 8192 blocks
  const int p = idx >> 11;
  const int n = idx & 2047;
  wtp[idx] = packh2(wt[(size_t)(2 * p) * 2048 + n], wt[(size_t)(2 * p + 1) * 2048 + n]);
}

// ---------------- Phase D: logits GEMM (fdot2, 128x128 tile) ----------------
__global__ __launch_bounds__(256) void gemm_kernel(
    const uint32_t* __restrict__ A,  // [16384][1024] f16 pairs
    const uint32_t* __restrict__ B,  // [1024][2048] f16 pairs
    const float* __restrict__ bias, float* __restrict__ C) {
  __shared__ __align__(16) uint32_t As[16 * 132];
  __shared__ __align__(16) uint32_t Bs[16 * 132];
  const int tid = threadIdx.x;
  const int bx = blockIdx.x;
  const int m0 = (bx >> 4) * 128;
  const int n0 = (bx & 15) * 128;
  const int tm = (tid & 15) * 8;
  const int tn = (tid >> 4) * 8;
  float acc[8][8];
#pragma unroll
  for (int i = 0; i < 8; ++i)
#pragma unroll
    for (int j = 0; j < 8; ++j) acc[i][j] = 0.f;
  for (int kt = 0; kt < 64; ++kt) {
    const int p0 = kt * 16;
    __syncthreads();
#pragma unroll
    for (int r = 0; r < 8; ++r) {
      int idx = r * 256 + tid;
      int m = idx >> 4, pp = idx & 15;
      As[pp * 132 + m] = A[(size_t)(m0 + m) * 1024 + p0 + pp];
    }
#pragma unroll
    for (int r = 0; r < 8; ++r) {
      int idx = r * 256 + tid;
      int pp = idx >> 7, n = idx & 127;
      Bs[pp * 132 + n] = B[(size_t)(p0 + pp) * 2048 + n0 + n];
    }
    __syncthreads();
#pragma unroll
    for (int pp = 0; pp < 16; ++pp) {
      const uint4* ap = (const uint4*)(As + pp * 132 + tm);
      const uint4* bp = (const uint4*)(Bs + pp * 132 + tn);
      uint4 a0 = ap[0], a1 = ap[1];
      uint4 b0 = bp[0], b1 = bp[1];
      uint32_t av[8] = {a0.x, a0.y, a0.z, a0.w, a1.x, a1.y, a1.z, a1.w};
      uint32_t bv[8] = {b0.x, b0.y, b0.z, b0.w, b1.x, b1.y, b1.z, b1.w};
#pragma unroll
      for (int i = 0; i < 8; ++i)
#pragma unroll
        for (int j = 0; j < 8; ++j) acc[i][j] = dot2f(av[i], bv[j], acc[i][j]);
    }
  }
#pragma unroll
  for (int i = 0; i < 8; ++i) {
    const int m = m0 + tm + i;
    float4 o0, o1;
    o0.x = acc[i][0] + bias[n0 + tn + 0];
    o0.y = acc[i][1] + bias[n0 + tn + 1];
    o0.z = acc[i][2] + bias[n0 + tn + 2];
    o0.w = acc[i][3] + bias[n0 + tn + 3];
    o1.x = acc[i][4] + bias[n0 + tn + 4];
    o1.y = acc[i][5] + bias[n0 + tn + 5];
    o1.z = acc[i][6] + bias[n0 + tn + 6];
    o1.w = acc[i][7] + bias[n0 + tn + 7];
    *(float4*)(C + (size_t)m * 2048 + n0 + tn) = o0;
    *(float4*)(C + (size_t)m * 2048 + n0 + tn + 4) = o1;
  }
}

// ---------------- Phase E: row-wise log_softmax in place ----------------
__global__ __launch_bounds__(256) void lsm_kernel(float* __restrict__ C) {
  __shared__ float red[8];
  const int row = blockIdx.x;
  float* p = C + (size_t)row * HID;
  const int tid = threadIdx.x, lane = tid & 63, wv = tid >> 6;
  float v[8];
  float4 q0 = *(const float4*)(p + tid * 8);
  float4 q1 = *(const float4*)(p + tid * 8 + 4);
  v[0] = q0.x; v[1] = q0.y; v[2] = q0.z; v[3] = q0.w;
  v[4] = q1.x; v[5] = q1.y; v[6] = q1.z; v[7] = q1.w;
  float mx = v[0];
#pragma unroll
  for (int i = 1; i < 8; ++i) mx = fmaxf(mx, v[i]);
#pragma unroll
  for (int m = 32; m >= 1; m >>= 1) mx = fmaxf(mx, __shfl_xor(mx, m, 64));
  if (lane == 0) red[wv] = mx;
  __syncthreads();
  mx = fmaxf(fmaxf(red[0], red[1]), fmaxf(red[2], red[3]));
  float sm = 0.f;
#pragma unroll
  for (int i = 0; i < 8; ++i) {
    v[i] -= mx;
    sm += __expf(v[i]);
  }
#pragma unroll
  for (int m = 32; m >= 1; m >>= 1) sm += __shfl_xor(sm, m, 64);
  if (lane == 0) red[4 + wv] = sm;
  __syncthreads();
  sm = red[4] + red[5] + red[6] + red[7];
  const float ls = __logf(sm);
#pragma unroll
  for (int i = 0; i < 8; ++i) v[i] -= ls;
  q0.x = v[0]; q0.y = v[1]; q0.z = v[2]; q0.w = v[3];
  q1.x = v[4]; q1.y = v[5]; q1.z = v[6]; q1.w = v[7];
  *(float4*)(p + tid * 8) = q0;
  *(float4*)(p + tid * 8 + 4) = q1;
}

extern "C" void kernel_launch(void* const* d_in, const int* in_sizes, int n_in,
                              void* d_out, int out_size, void* d_ws, size_t ws_size,
                              hipStream_t stream) {
  const float* sent = (const float*)d_in[0];
  const float* fm_w = (const float*)d_in[1];
  const float* fm_b = (const float*)d_in[2];
  const float* c1w = (const float*)d_in[3];
  const float* c1b = (const float*)d_in[4];
  const float* p1w = (const float*)d_in[5];
  const float* p1b = (const float*)d_in[6];
  const float* c2w = (const float*)d_in[7];
  const float* c2b = (const float*)d_in[8];
  const float* p2w = (const float*)d_in[9];
  const float* p2b = (const float*)d_in[10];
  const float* c3w = (const float*)d_in[11];
  const float* c3b = (const float*)d_in[12];
  const float* hw = (const float*)d_in[13];
  const float* hb = (const float*)d_in[14];
  const float* wf = (const float*)d_in[15];
  const float* bf = (const float*)d_in[16];
  const float* wi = (const float*)d_in[17];
  const float* bi = (const float*)d_in[18];
  const float* wu = (const float*)d_in[19];
  const float* bu = (const float*)d_in[20];
  const float* wo = (const float*)d_in[21];
  const float* bo = (const float*)d_in[22];
  const float* wt = (const float*)d_in[23];
  const float* bt = (const float*)d_in[24];

  char* ws = (char*)d_ws;
  float* seq = (float*)ws;                                          // 64KB
  unsigned long long* hbuf = (unsigned long long*)(ws + 65536);     // 16KB
  uint32_t* hseq = (uint32_t*)(ws + 131072);                        // 64MB
  uint32_t* wtp = (uint32_t*)(ws + 131072 + (size_t)S_LEN * NPAIR * 4);  // 8MB
  float* C = (float*)d_out;

  qcnn_kernel<<<64, 256, 0, stream>>>(sent, fm_w, fm_b, c1w, c1b, p1w, p1b, c2w, c2b,
                                      p2w, p2b, c3w, c3b, hw, hb, seq, hbuf);
  packwt_kernel<<<8192, 256, 0, stream>>>(wt, wtp);

  void* args[] = {(void*)&seq, (void*)&wf, (void*)&bf, (void*)&wi, (void*)&bi,
                  (void*)&wu, (void*)&bu, (void*)&wo, (void*)&bo,
                  (void*)&hbuf, (void*)&hseq};
  hipError_t rc = hipLaunchCooperativeKernel((void*)lstm_kernel, dim3(256), dim3(256),
                                             args, 0, stream);
  if (rc != hipSuccess) {
    // 139.5KB LDS forces 1 block/CU; grid == 256 == #CUs, so all blocks
    // are co-resident even under a plain launch.
    lstm_kernel<<<256, 256, 0, stream>>>(seq, wf, bf, wi, bi, wu, bu, wo, bo, hbuf, hseq);
  }

  gemm_kernel<<<2048, 256, 0, stream>>>(hseq, wtp, bt, C);
  lsm_kernel<<<16384, 256, 0, stream>>>(C);
}

// Round 2
// 40896.664 us; speedup vs baseline: 1.8485x; 1.8485x over previous
//
#include <hip/hip_runtime.h>
#include <stdint.h>

#define S_LEN 16384
#define HID 2048
#define NPAIR 1024   // h pairs (2048/2)

typedef _Float16 h2v __attribute__((ext_vector_type(2)));

__device__ __forceinline__ float dot2f(uint32_t a, uint32_t b, float c) {
#if __has_builtin(__builtin_amdgcn_fdot2)
  return __builtin_amdgcn_fdot2(__builtin_bit_cast(h2v, a), __builtin_bit_cast(h2v, b), c, false);
#else
  h2v ha = __builtin_bit_cast(h2v, a), hb = __builtin_bit_cast(h2v, b);
  return c + (float)ha[0] * (float)hb[0] + (float)ha[1] * (float)hb[1];
#endif
}

__device__ __forceinline__ uint32_t packh2(float a, float b) {
  h2v h; h[0] = (_Float16)a; h[1] = (_Float16)b;
  return __builtin_bit_cast(uint32_t, h);
}

__device__ __forceinline__ float fsig(float x) { return 1.0f / (1.0f + __expf(-x)); }
__device__ __forceinline__ float ftanh(float x) { return 2.0f / (1.0f + __expf(-2.0f * x)) - 1.0f; }

// Wave64 sum via DPP (VALU pipe only, no DS ops). Valid result in lane 63.
__device__ __forceinline__ float wave_reduce_add(float x) {
#define DPP_STEP(ctrl)                                                                   \
  {                                                                                      \
    int t_ = __builtin_amdgcn_update_dpp(0, __builtin_bit_cast(int, x), ctrl, 0xf, 0xf, true); \
    x += __builtin_bit_cast(float, t_);                                                  \
  }
  DPP_STEP(0x111)  // row_shr:1
  DPP_STEP(0x112)  // row_shr:2
  DPP_STEP(0x114)  // row_shr:4
  DPP_STEP(0x118)  // row_shr:8
  DPP_STEP(0x142)  // row_bcast:15
  DPP_STEP(0x143)  // row_bcast:31
#undef DPP_STEP
  return x;
}

// ---------------- Phase A: QCNN MLP per token + hbuf init ----------------
__global__ __launch_bounds__(256) void qcnn_kernel(
    const float* __restrict__ sent,
    const float* __restrict__ fm_w, const float* __restrict__ fm_b,
    const float* __restrict__ c1w, const float* __restrict__ c1b,
    const float* __restrict__ p1w, const float* __restrict__ p1b,
    const float* __restrict__ c2w, const float* __restrict__ c2b,
    const float* __restrict__ p2w, const float* __restrict__ p2b,
    const float* __restrict__ c3w, const float* __restrict__ c3b,
    const float* __restrict__ hw, const float* __restrict__ hb,
    float* __restrict__ seq, unsigned long long* __restrict__ hbuf) {
  __shared__ float w[720];
  const int tid = threadIdx.x;
  const float* srcs[14] = {fm_w, fm_b, c1w, c1b, p1w, p1b, c2w, c2b, p2w, p2b, c3w, c3b, hw, hb};
  const int offs[14] = {0, 128, 144, 400, 416, 608, 620, 668, 672, 688, 692, 708, 712, 716};
  const int cnts[14] = {128, 16, 256, 16, 192, 12, 48, 4, 16, 4, 16, 4, 4, 1};
  for (int a = 0; a < 14; ++a)
    for (int i = tid; i < cnts[a]; i += 256) w[offs[a] + i] = srcs[a][i];
  if (blockIdx.x == 0) {
    for (int p = tid; p < NPAIR; p += 256) {
      hbuf[p] = 0ull;                         // slot0: tag 0, h(-1)=0
      hbuf[NPAIR + p] = 0x7FFFFFFFull << 32;  // slot1: invalid tag
    }
  }
  __syncthreads();
  const int t = blockIdx.x * 256 + tid;
  float x[8];
#pragma unroll
  for (int i = 0; i < 8; ++i) x[i] = sent[t * 8 + i];
  float a0[16], a1[16], a2[12], a3[4], a4[4], a5[4];
#pragma unroll
  for (int o = 0; o < 16; ++o) {
    float s = w[128 + o];
#pragma unroll
    for (int i = 0; i < 8; ++i) s += x[i] * w[i * 16 + o];
    a0[o] = ftanh(s);
  }
#pragma unroll
  for (int o = 0; o < 16; ++o) {
    float s = w[400 + o];
#pragma unroll
    for (int i = 0; i < 16; ++i) s += a0[i] * w[144 + i * 16 + o];
    a1[o] = ftanh(s);
  }
#pragma unroll
  for (int o = 0; o < 12; ++o) {
    float s = w[608 + o];
#pragma unroll
    for (int i = 0; i < 16; ++i) s += a1[i] * w[416 + i * 12 + o];
    a2[o] = ftanh(s);
  }
#pragma unroll
  for (int o = 0; o < 4; ++o) {
    float s = w[668 + o];
#pragma unroll
    for (int i = 0; i < 12; ++i) s += a2[i] * w[620 + i * 4 + o];
    a3[o] = ftanh(s);
  }
#pragma unroll
  for (int o = 0; o < 4; ++o) {
    float s = w[688 + o];
#pragma unroll
    for (int i = 0; i < 4; ++i) s += a3[i] * w[672 + i * 4 + o];
    a4[o] = ftanh(s);
  }
#pragma unroll
  for (int o = 0; o < 4; ++o) {
    float s = w[708 + o];
#pragma unroll
    for (int i = 0; i < 4; ++i) s += a4[i] * w[692 + i * 4 + o];
    a5[o] = ftanh(s);
  }
  float s = w[716];
#pragma unroll
  for (int i = 0; i < 4; ++i) s += a5[i] * w[712 + i];
  seq[t] = fsig(s);
}

// ---------------- Phase B: persistent LSTM scan (weights in VGPRs) ----------------
// 256 blocks x 512 threads (8 waves, 2/SIMD). Wave wv owns hidden unit col = blk*8+wv.
// Per lane: 64 packed-f16 weight u32s in VGPRs (4 gates x 16 h-pairs).
// Per step: 8-way parallel poll (2 tagged u64/lane) -> LDS bounce -> 4x ds_read_b128
// of h -> 64 v_dot2 -> DPP wave reduce (VALU only) -> gate math on lane 63 ->
// tagged u64 atomic store (agent scope) for the next step.
__global__ __launch_bounds__(512, 2) void lstm_kernel(
    const float* __restrict__ seq,
    const float* __restrict__ wfp, const float* __restrict__ bfp,
    const float* __restrict__ wip, const float* __restrict__ bip,
    const float* __restrict__ wup, const float* __restrict__ bup,
    const float* __restrict__ wop, const float* __restrict__ bop,
    unsigned long long* __restrict__ hbuf,
    uint16_t* __restrict__ hseq) {
  __shared__ __align__(16) uint32_t smem[32768];  // 128 KB
  const int tid = threadIdx.x;
  const int lane = tid & 63;
  const int wv = tid >> 6;  // 0..7
  const int blk = blockIdx.x;
  const int col = blk * 8 + wv;
  const float* wptr[4] = {wfp, wip, wup, wop};
  const float* bptr[4] = {bfp, bip, bup, bop};

  // ---- stage packed-f16 weights into LDS (temporary) ----
  {
    const int jj = tid & 7;
    const int sc = blk * 8 + jj;
    const int pb = tid >> 3;  // 0..63
#pragma unroll
    for (int g = 0; g < 4; ++g) {
      const float* wsp = wptr[g];
      for (int pp = 0; pp < 16; ++pp) {
        int p = pp * 64 + pb;
        float w0 = wsp[(size_t)(1 + 2 * p) * HID + sc];
        float w1 = wsp[(size_t)(2 + 2 * p) * HID + sc];
        smem[(jj * 1024 + p) * 4 + g] = packh2(w0, w1);
      }
    }
  }
  __syncthreads();
  // ---- LDS -> VGPRs: wr[m][j][g] = gate-g weight pair (256m + 4*lane + j) ----
  uint32_t wr[4][4][4];
#pragma unroll
  for (int m = 0; m < 4; ++m)
#pragma unroll
    for (int j = 0; j < 4; ++j) {
      const uint4 q = *(const uint4*)&smem[(wv * 1024 + 256 * m + 4 * lane + j) * 4];
      wr[m][j][0] = q.x; wr[m][j][1] = q.y; wr[m][j][2] = q.z; wr[m][j][3] = q.w;
    }
  float wx[4], bb[4];
#pragma unroll
  for (int g = 0; g < 4; ++g) {
    wx[g] = wptr[g][col];  // row 0 = x coefficient
    bb[g] = bptr[g][col];
  }
  __syncthreads();
  // ---- repurpose LDS: [0,64K) = seq, [64K,72K) = h double buffer, +32B = hx ----
  float* seqf = (float*)smem;
  for (int i = tid; i < 4096; i += 512) ((float4*)seqf)[i] = ((const float4*)seq)[i];
  uint32_t* hlds = smem + 16384;
  uint16_t* hx16 = (uint16_t*)(smem + 18432);
  __syncthreads();

  float cell = 0.f;
  for (int s = 0; s < S_LEN; ++s) {
    const int slot = s & 1;
    uint32_t* hl = hlds + slot * NPAIR;
    const float xt = seqf[s];
    // -- poll my 2 chunks (128 pairs) --
    unsigned long long* src = hbuf + (size_t)slot * NPAIR + wv * 128 + lane;
    unsigned long long h0 = __hip_atomic_load(src, __ATOMIC_RELAXED, __HIP_MEMORY_SCOPE_AGENT);
    unsigned long long h1 = __hip_atomic_load(src + 64, __ATOMIC_RELAXED, __HIP_MEMORY_SCOPE_AGENT);
    const uint32_t want = (uint32_t)s;
    while (true) {
      const bool ok0 = ((uint32_t)(h0 >> 32) == want);
      const bool ok1 = ((uint32_t)(h1 >> 32) == want);
      if (__all(ok0 && ok1)) break;
      __builtin_amdgcn_s_sleep(1);
      if (!ok0) h0 = __hip_atomic_load(src, __ATOMIC_RELAXED, __HIP_MEMORY_SCOPE_AGENT);
      if (!ok1) h1 = __hip_atomic_load(src + 64, __ATOMIC_RELAXED, __HIP_MEMORY_SCOPE_AGENT);
    }
    hl[wv * 128 + lane] = (uint32_t)h0;
    hl[wv * 128 + 64 + lane] = (uint32_t)h1;
    __syncthreads();
    // -- matvec: 64 dot2 from VGPR weights, h via 4 contiguous b128 reads --
    float a0 = 0.f, a1 = 0.f, a2 = 0.f, a3 = 0.f;
#pragma unroll
    for (int m = 0; m < 4; ++m) {
      const uint4 q = *(const uint4*)&hl[256 * m + 4 * lane];
      a0 = dot2f(wr[m][0][0], q.x, a0);
      a1 = dot2f(wr[m][0][1], q.x, a1);
      a2 = dot2f(wr[m][0][2], q.x, a2);
      a3 = dot2f(wr[m][0][3], q.x, a3);
      a0 = dot2f(wr[m][1][0], q.y, a0);
      a1 = dot2f(wr[m][1][1], q.y, a1);
      a2 = dot2f(wr[m][1][2], q.y, a2);
      a3 = dot2f(wr[m][1][3], q.y, a3);
      a0 = dot2f(wr[m][2][0], q.z, a0);
      a1 = dot2f(wr[m][2][1], q.z, a1);
      a2 = dot2f(wr[m][2][2], q.z, a2);
      a3 = dot2f(wr[m][2][3], q.z, a3);
      a0 = dot2f(wr[m][3][0], q.w, a0);
      a1 = dot2f(wr[m][3][1], q.w, a1);
      a2 = dot2f(wr[m][3][2], q.w, a2);
      a3 = dot2f(wr[m][3][3], q.w, a3);
    }
    a0 = wave_reduce_add(a0);
    a1 = wave_reduce_add(a1);
    a2 = wave_reduce_add(a2);
    a3 = wave_reduce_add(a3);
    if (lane == 63) {
      const float pF = a0 + wx[0] * xt + bb[0];
      const float pI = a1 + wx[1] * xt + bb[1];
      const float pU = a2 + wx[2] * xt + bb[2];
      const float pO = a3 + wx[3] * xt + bb[3];
      cell = fsig(pF) * cell + fsig(pI) * ftanh(pU);
      const float hval = fsig(pO) * ftanh(cell);
      const _Float16 hf = (_Float16)hval;
      const uint16_t hbits = __builtin_bit_cast(uint16_t, hf);
      hseq[(size_t)s * HID + col] = hbits;
      hx16[wv] = hbits;
    }
    __syncthreads();
    if (tid < 4) {
      const uint32_t pk = smem[18432 + tid];  // {col 8b+2t, col 8b+2t+1} as 2xf16
      const unsigned long long val =
          (((unsigned long long)(uint32_t)(s + 1)) << 32) | (unsigned long long)pk;
      __hip_atomic_store(hbuf + (size_t)((s + 1) & 1) * NPAIR + blk * 4 + tid, val,
                         __ATOMIC_RELAXED, __HIP_MEMORY_SCOPE_AGENT);
    }
  }
}

// ---------------- Phase C: wt pre-pack to f16 pairs ----------------
__global__ __launch_bounds__(256) void packwt_kernel(const float* __restrict__ wt,
                                                     uint32_t* __restrict__ wtp) {
  const int idx = blockIdx.x * 256 + threadIdx.x;
  const int p = idx >> 11;
  const int n = idx & 2047;
  wtp[idx] = packh2(wt[(size_t)(2 * p) * 2048 + n], wt[(size_t)(2 * p + 1) * 2048 + n]);
}

// ---------------- Phase D: logits GEMM (fdot2, 128x128 tile) ----------------
__global__ __launch_bounds__(256) void gemm_kernel(
    const uint32_t* __restrict__ A,  // [16384][1024] f16 pairs
    const uint32_t* __restrict__ B,  // [1024][2048] f16 pairs
    const float* __restrict__ bias, float* __restrict__ C) {
  __shared__ __align__(16) uint32_t As[16 * 132];
  __shared__ __align__(16) uint32_t Bs[16 * 132];
  const int tid = threadIdx.x;
  const int bx = blockIdx.x;
  const int m0 = (bx >> 4) * 128;
  const int n0 = (bx & 15) * 128;
  const int tm = (tid & 15) * 8;
  const int tn = (tid >> 4) * 8;
  float acc[8][8];
#pragma unroll
  for (int i = 0; i < 8; ++i)
#pragma unroll
    for (int j = 0; j < 8; ++j) acc[i][j] = 0.f;
  for (int kt = 0; kt < 64; ++kt) {
    const int p0 = kt * 16;
    __syncthreads();
#pragma unroll
    for (int r = 0; r < 8; ++r) {
      int idx = r * 256 + tid;
      int m = idx >> 4, pp = idx & 15;
      As[pp * 132 + m] = A[(size_t)(m0 + m) * 1024 + p0 + pp];
    }
#pragma unroll
    for (int r = 0; r < 8; ++r) {
      int idx = r * 256 + tid;
      int pp = idx >> 7, n = idx & 127;
      Bs[pp * 132 + n] = B[(size_t)(p0 + pp) * 2048 + n0 + n];
    }
    __syncthreads();
#pragma unroll
    for (int pp = 0; pp < 16; ++pp) {
      const uint4* ap = (const uint4*)(As + pp * 132 + tm);
      const uint4* bp = (const uint4*)(Bs + pp * 132 + tn);
      uint4 a0 = ap[0], a1 = ap[1];
      uint4 b0 = bp[0], b1 = bp[1];
      uint32_t av[8] = {a0.x, a0.y, a0.z, a0.w, a1.x, a1.y, a1.z, a1.w};
      uint32_t bv[8] = {b0.x, b0.y, b0.z, b0.w, b1.x, b1.y, b1.z, b1.w};
#pragma unroll
      for (int i = 0; i < 8; ++i)
#pragma unroll
        for (int j = 0; j < 8; ++j) acc[i][j] = dot2f(av[i], bv[j], acc[i][j]);
    }
  }
#pragma unroll
  for (int i = 0; i < 8; ++i) {
    const int m = m0 + tm + i;
    float4 o0, o1;
    o0.x = acc[i][0] + bias[n0 + tn + 0];
    o0.y = acc[i][1] + bias[n0 + tn + 1];
    o0.z = acc[i][2] + bias[n0 + tn + 2];
    o0.w = acc[i][3] + bias[n0 + tn + 3];
    o1.x = acc[i][4] + bias[n0 + tn + 4];
    o1.y = acc[i][5] + bias[n0 + tn + 5];
    o1.z = acc[i][6] + bias[n0 + tn + 6];
    o1.w = acc[i][7] + bias[n0 + tn + 7];
    *(float4*)(C + (size_t)m * 2048 + n0 + tn) = o0;
    *(float4*)(C + (size_t)m * 2048 + n0 + tn + 4) = o1;
  }
}

// ---------------- Phase E: row-wise log_softmax in place ----------------
__global__ __launch_bounds__(256) void lsm_kernel(float* __restrict__ C) {
  __shared__ float red[8];
  const int row = blockIdx.x;
  float* p = C + (size_t)row * HID;
  const int tid = threadIdx.x, lane = tid & 63, wv = tid >> 6;
  float v[8];
  float4 q0 = *(const float4*)(p + tid * 8);
  float4 q1 = *(const float4*)(p + tid * 8 + 4);
  v[0] = q0.x; v[1] = q0.y; v[2] = q0.z; v[3] = q0.w;
  v[4] = q1.x; v[5] = q1.y; v[6] = q1.z; v[7] = q1.w;
  float mx = v[0];
#pragma unroll
  for (int i = 1; i < 8; ++i) mx = fmaxf(mx, v[i]);
#pragma unroll
  for (int m = 32; m >= 1; m >>= 1) mx = fmaxf(mx, __shfl_xor(mx, m, 64));
  if (lane == 0) red[wv] = mx;
  __syncthreads();
  mx = fmaxf(fmaxf(red[0], red[1]), fmaxf(red[2], red[3]));
  float sm = 0.f;
#pragma unroll
  for (int i = 0; i < 8; ++i) {
    v[i] -= mx;
    sm += __expf(v[i]);
  }
#pragma unroll
  for (int m = 32; m >= 1; m >>= 1) sm += __shfl_xor(sm, m, 64);
  if (lane == 0) red[4 + wv] = sm;
  __syncthreads();
  sm = red[4] + red[5] + red[6] + red[7];
  const float ls = __logf(sm);
#pragma unroll
  for (int i = 0; i < 8; ++i) v[i] -= ls;
  q0.x = v[0]; q0.y = v[1]; q0.z = v[2]; q0.w = v[3];
  q1.x = v[4]; q1.y = v[5]; q1.z = v[6]; q1.w = v[7];
  *(float4*)(p + tid * 8) = q0;
  *(float4*)(p + tid * 8 + 4) = q1;
}

extern "C" void kernel_launch(void* const* d_in, const int* in_sizes, int n_in,
                              void* d_out, int out_size, void* d_ws, size_t ws_size,
                              hipStream_t stream) {
  const float* sent = (const float*)d_in[0];
  const float* fm_w = (const float*)d_in[1];
  const float* fm_b = (const float*)d_in[2];
  const float* c1w = (const float*)d_in[3];
  const float* c1b = (const float*)d_in[4];
  const float* p1w = (const float*)d_in[5];
  const float* p1b = (const float*)d_in[6];
  const float* c2w = (const float*)d_in[7];
  const float* c2b = (const float*)d_in[8];
  const float* p2w = (const float*)d_in[9];
  const float* p2b = (const float*)d_in[10];
  const float* c3w = (const float*)d_in[11];
  const float* c3b = (const float*)d_in[12];
  const float* hw = (const float*)d_in[13];
  const float* hb = (const float*)d_in[14];
  const float* wf = (const float*)d_in[15];
  const float* bf = (const float*)d_in[16];
  const float* wi = (const float*)d_in[17];
  const float* bi = (const float*)d_in[18];
  const float* wu = (const float*)d_in[19];
  const float* bu = (const float*)d_in[20];
  const float* wo = (const float*)d_in[21];
  const float* bo = (const float*)d_in[22];
  const float* wt = (const float*)d_in[23];
  const float* bt = (const float*)d_in[24];

  char* ws = (char*)d_ws;
  float* seq = (float*)ws;                                       // 64KB
  unsigned long long* hbuf = (unsigned long long*)(ws + 65536);  // 16KB
  uint16_t* hseq = (uint16_t*)(ws + 131072);                     // 64MB
  uint32_t* wtp = (uint32_t*)(ws + 131072 + (size_t)S_LEN * HID * 2);  // 8MB
  float* C = (float*)d_out;

  qcnn_kernel<<<64, 256, 0, stream>>>(sent, fm_w, fm_b, c1w, c1b, p1w, p1b, c2w, c2b,
                                      p2w, p2b, c3w, c3b, hw, hb, seq, hbuf);
  packwt_kernel<<<8192, 256, 0, stream>>>(wt, wtp);

  void* args[] = {(void*)&seq, (void*)&wf, (void*)&bf, (void*)&wi, (void*)&bi,
                  (void*)&wu, (void*)&bu, (void*)&wo, (void*)&bo,
                  (void*)&hbuf, (void*)&hseq};
  hipError_t rc = hipLaunchCooperativeKernel((void*)lstm_kernel, dim3(256), dim3(512),
                                             args, 0, stream);
  if (rc != hipSuccess) {
    // 128KB LDS forces 1 block/CU; grid == 256 == #CUs, so all blocks
    // are co-resident even under a plain launch.
    lstm_kernel<<<256, 512, 0, stream>>>(seq, wf, bf, wi, bi, wu, bu, wo, bo, hbuf, hseq);
  }

  gemm_kernel<<<2048, 256, 0, stream>>>((const uint32_t*)hseq, wtp, bt, C);
  lsm_kernel<<<16384, 256, 0, stream>>>(C);
}